// Round 5
// baseline (234.155 us; speedup 1.0000x reference)
//
#include <hip/hip_runtime.h>

// IDWT 2D (Haar 2x2 filter bank), R9.
//
// Evidence through R8:
//   - Four structurally different kernels (NT 1px, dword 4px, dwordx4,
//     pipelined SGPR-filter 16px) ALL land at 75-83 us -> limit is the
//     memory system serving this footprint, not instruction mix.
//   - Counters: FETCH=64 MiB (half of input survives L3), WRITE=128 MiB
//     exact (NO inflation -> R0's reason for dropping NT stores was wrong).
//   - Harness fill: 6.7 TB/s write-only @ 9% occupancy; copy ubench 6.3 TB/s
//     mixed. We run 2.5 TB/s HBM-side. Differentiator: our cached output
//     stores ALLOCATE 128 MiB/iter in L2/L3, evicting the input.
//
// R9 = R8 + __builtin_nontemporal_store on the output (ONE variable).
// Output is write-once-never-read: allocation is pure pollution. Goal:
// input stays L3-resident -> FETCH drops, HBM bytes drop, read latency drops.
//
// Prediction: WRITE unchanged 128 MiB; FETCH 64 -> <=48 MiB; kernel
// 79.6 -> 60-70 us; dur_us 231 -> 210-220. If unchanged: structural floor,
// declare roofline-with-harness-floor.

typedef float floatx4 __attribute__((ext_vector_type(4)));

constexpr long SUB_STRIDE = 1L << 20;   // C*H*W floats (4 MiB per subband)
constexpr long P_TOTAL    = 8L << 20;   // 8,388,608 pixels
constexpr int  BLOCKS     = 2048;       // 8 blocks/CU
constexpr int  PIX_PER_BLOCK = (int)(P_TOTAL / BLOCKS);  // 4096

#define LOAD_GROUP(dst, IT)                                            \
    _Pragma("unroll") for (int k = 0; k < 4; ++k)                      \
    _Pragma("unroll") for (int t = 0; t < 4; ++t)                      \
        dst[k][t] = xk[k][(IT) * 1024 + t * 64];

#define COMPUTE_STORE(src, IT)                                         \
    _Pragma("unroll") for (int t = 0; t < 4; ++t) {                    \
        floatx4 r;                                                     \
        _Pragma("unroll") for (int ab = 0; ab < 4; ++ab)               \
            r[ab] = fs[ab]      * src[0][t] + fs[4 + ab]  * src[1][t]  \
                  + fs[8 + ab]  * src[2][t] + fs[12 + ab] * src[3][t]; \
        __builtin_nontemporal_store(r, &o4[(IT) * 1024 + t * 64]);     \
    }

__global__ __launch_bounds__(256) void idwt2d_kernel(
    const float* __restrict__ x,
    const float* __restrict__ f,
    float* __restrict__ out)
{
    const int lane = threadIdx.x & 63;
    const int wv   = threadIdx.x >> 6;

    // Block owns pixels [PB, PB+4096). 4096 | 2^20, so n is block-uniform.
    const long PB = (long)blockIdx.x * PIX_PER_BLOCK;
    const long n  = PB >> 20;

    // Filters into SGPRs (wave-uniform by construction).
    float fs[16];
#pragma unroll
    for (int i = 0; i < 16; ++i)
        fs[i] = __uint_as_float(
            (unsigned)__builtin_amdgcn_readfirstlane((int)__float_as_uint(f[i])));

    // Per-thread stream bases. Thread offset within block chunk: wv*256+lane.
    const long toff = (long)wv * 256 + lane;
    const float* xk[4];
#pragma unroll
    for (int k = 0; k < 4; ++k)
        xk[k] = x + PB + (3 * n + k) * SUB_STRIDE + toff;
    floatx4* o4 = (floatx4*)out + PB + toff;   // out float offset = 4*pixel

    // Software pipeline, 2 deep, 4 groups of 1024 pixels. All indices static.
    float A[4][4], Bf[4][4];
    LOAD_GROUP(A, 0)
    LOAD_GROUP(Bf, 1)
    COMPUTE_STORE(A, 0)
    LOAD_GROUP(A, 2)
    COMPUTE_STORE(Bf, 1)
    LOAD_GROUP(Bf, 3)
    COMPUTE_STORE(A, 2)
    COMPUTE_STORE(Bf, 3)
}

extern "C" void kernel_launch(void* const* d_in, const int* in_sizes, int n_in,
                              void* d_out, int out_size, void* d_ws, size_t ws_size,
                              hipStream_t stream)
{
    const float* x   = (const float*)d_in[0];
    const float* flt = (const float*)d_in[1];
    float* out       = (float*)d_out;

    idwt2d_kernel<<<BLOCKS, 256, 0, stream>>>(x, flt, out);
}

// Round 6
// 229.226 us; speedup vs baseline: 1.0215x; 1.0215x over previous
//
#include <hip/hip_runtime.h>

// IDWT 2D (Haar 2x2 filter bank), R10.
//
// Evidence through R9: five structurally different kernels all land 69-82 us
// with compulsory-minimal traffic (FETCH 64 MiB w/ L3 hits, WRITE exactly
// 128 MiB), VALUBusy ~2.5%, zero bank conflicts, abundant in-flight loads.
// NT stores: neutral. Meanwhile fill = 6.7 TB/s @ 9% occupancy and copy
// ubench = 6.3 TB/s mixed. The ONE property shared by all our variants and
// by neither fast kernel: FOUR concurrent read streams per wave at 4 MiB
// (2^22 B) stride -> lockstep same-phase requests into the HBM channel
// interleave.
//
// R10: one stream per wave via LDS staging.
//   - Block (4 waves) owns 2048 contiguous pixels. Wave k stages subband k's
//     8 KB slice: 8x dwordx4, 1 KiB contiguous per instr, ALL sequential
//     addresses (single stream per wave).
//   - barrier; then 256 threads compute 8 pixels each: 4x ds_read_b32
//     (lane stride 4 B, conflict-free) + FMA + 1 KiB-contiguous dwordx4
//     stores (out is exactly float4[pixel]).
//   - LDS 32 KB -> 5 blocks/CU; cross-block overlap hides stage/compute
//     serialization.
//
// Prediction: FETCH/WRITE unchanged; stream-theory right -> kernel 80->50-60,
// dur 234->200-215. Unchanged -> platform floor; declare roofline next round.

typedef float floatx4 __attribute__((ext_vector_type(4)));

constexpr long SUB_STRIDE = 1L << 20;    // C*H*W floats (4 MiB per subband)
constexpr long P_TOTAL    = 8L << 20;    // 8,388,608 pixels
constexpr int  G          = 2048;        // pixels per block
constexpr int  BLOCKS     = (int)(P_TOTAL / G);  // 4096

__global__ __launch_bounds__(256) void idwt2d_kernel(
    const float* __restrict__ x,
    const float* __restrict__ f,
    float* __restrict__ out)
{
    __shared__ float lds[4][G];          // 32 KB

    const int tid  = threadIdx.x;
    const int lane = tid & 63;
    const int wv   = tid >> 6;

    // Block owns pixels [PB, PB+2048). 2048 | 2^20 -> n is block-uniform.
    const long PB = (long)blockIdx.x * G;
    const long n  = PB >> 20;

    // Filters into SGPRs (wave-uniform).
    float fs[16];
#pragma unroll
    for (int i = 0; i < 16; ++i)
        fs[i] = __uint_as_float(
            (unsigned)__builtin_amdgcn_readfirstlane((int)__float_as_uint(f[i])));

    // Stage: wave wv loads subband wv's 2048 floats (8 KB, single stream).
    {
        const floatx4* src = (const floatx4*)(x + PB + (3 * n + wv) * SUB_STRIDE);
        floatx4*       dst = (floatx4*)lds[wv];
#pragma unroll
        for (int i = 0; i < G / 4 / 64; ++i)          // 8 iterations
            dst[i * 64 + lane] = src[i * 64 + lane];
    }
    __syncthreads();

    // Compute: pixel p = tid + j*256; stores 1 KiB contiguous per wave-instr.
    floatx4* o4 = (floatx4*)out + PB;                 // out = float4[pixel]
#pragma unroll
    for (int j = 0; j < G / 256; ++j) {               // 8 iterations
        const int p = tid + j * 256;
        const float v0 = lds[0][p];
        const float v1 = lds[1][p];
        const float v2 = lds[2][p];
        const float v3 = lds[3][p];
        floatx4 r;
#pragma unroll
        for (int ab = 0; ab < 4; ++ab)
            r[ab] = fs[ab] * v0 + fs[4 + ab] * v1
                  + fs[8 + ab] * v2 + fs[12 + ab] * v3;
        o4[p] = r;
    }
}

extern "C" void kernel_launch(void* const* d_in, const int* in_sizes, int n_in,
                              void* d_out, int out_size, void* d_ws, size_t ws_size,
                              hipStream_t stream)
{
    const float* x   = (const float*)d_in[0];
    const float* flt = (const float*)d_in[1];
    float* out       = (float*)d_out;

    idwt2d_kernel<<<BLOCKS, 256, 0, stream>>>(x, flt, out);
}